// Round 1
// baseline (369.798 us; speedup 1.0000x reference)
//
#include <hip/hip_runtime.h>
#include <stdint.h>

#define OBS 15
#define NTOT 50000
#define HDIM 64
#define NPB 32              // neighbors per block, 2 groups of 16
#define NBLK_N 1563         // ceil(50000/32); block 1562 has only group0 valid
#define ZOFF (OBS * NPB * 8) // ushort index of the 16B zero slot in xbf

typedef __attribute__((ext_vector_type(8))) short short8;
typedef __attribute__((ext_vector_type(4))) float f32x4;
typedef __attribute__((ext_vector_type(2))) unsigned int u32x2;
typedef __attribute__((ext_vector_type(4))) unsigned int u32x4;

static __device__ __forceinline__ unsigned short f2bf(float f) {
  unsigned u = __float_as_uint(f);
  u += 0x7fff + ((u >> 16) & 1);
  return (unsigned short)(u >> 16);
}
static __device__ __forceinline__ float bf2f(unsigned short b) {
  return __uint_as_float(((unsigned)b) << 16);
}
// RNE pack of two f32 -> 2 bf16 in one VALU inst (pure VALU asm, dep-tracked
// via constraints; no memory side effects so no sched_barrier needed).
static __device__ __forceinline__ unsigned cvtpk_bf16(float lo, float hi) {
  unsigned r;
  asm("v_cvt_pk_bf16_f32 %0, %1, %2" : "=v"(r) : "v"(lo), "v"(hi));
  return r;
}

#if __has_builtin(__builtin_amdgcn_exp2f)
#define EXP2F(x) __builtin_amdgcn_exp2f(x)
#else
#define EXP2F(x) exp2f(x)
#endif
#if __has_builtin(__builtin_amdgcn_rcpf)
#define RCPF(x) __builtin_amdgcn_rcpf(x)
#else
#define RCPF(x) (1.0f / (x))
#endif

static __device__ __forceinline__ float sigm(float x) {
  return RCPF(1.0f + EXP2F(-1.4426950408889634f * x));
}
static __device__ __forceinline__ float tanh_(float x) {
  return 2.0f * RCPF(1.0f + EXP2F(-2.8853900817779268f * x)) - 1.0f;
}

__global__ void k_zero(float* social) {
  social[threadIdx.x] = 0.0f;  // 1024 threads == 16*64 floats
}

#define MFMA_BF16 __builtin_amdgcn_mfma_f32_16x16x32_bf16

// Transposed-MFMA formulation: A-operand = W_hh rows (gates=M), B-operand =
// h columns (neighbors=N).  D row (g4*4+r) = gate-within-tile -> each thread
// owns 4 CONSECUTIVE hidden dims of ONE neighbor (t15): packed ds_write_b64
// h-write via v_cvt_pk_bf16_f32.  x*W_ih + bias folded into one MFMA per
// quadrant with an 8-row hi/lo scheme (error ~2^-18, << bf16-h error).
// launch_bounds(256,2): 256-VGPR budget; (256,4)/waves_per_eu(4) pinned VGPRs
// to 64 and spilled the persistent fragment set in earlier rounds.
__global__ __launch_bounds__(256, 2)
void k_neigh(
    const float* __restrict__ tgt,   // 15*1*2
    const float* __restrict__ oth,   // 15*N*2
    const int* __restrict__ mask,    // 15*N
    const float* __restrict__ W_ih,  // 256*2
    const float* __restrict__ b_ih,  // 256
    const float* __restrict__ W_hh,  // 256*64
    const float* __restrict__ b_hh,  // 256
    float* __restrict__ social,      // 16*64, pre-zeroed
    float* __restrict__ ht_out)      // 64 (target-LSTM final h)
{
  // [buf][grp][n=16 rows x 128B], bf16 h, XOR-swizzled (bits 4..6 by n&7)
  __shared__ __align__(16) unsigned char hbuf[2][2][2048];
  // per (t,n): 8 ushorts {x0hi,x0hi,x0lo,x1hi,x1hi,x1lo,1,1} + 16B zero slot
  __shared__ __align__(16) unsigned short xbf[ZOFF + 8];
  __shared__ float xs14[NPB][2];
  __shared__ float tht[HDIM];
  __shared__ float tgb[256];

  const int tid = threadIdx.x;

  if (blockIdx.x == NBLK_N) {
    // ---- target LSTM, fp32 exact; runs concurrently with neighbor blocks ----
    const float bias = b_ih[tid] + b_hh[tid];
    const float wi0 = W_ih[tid * 2], wi1 = W_ih[tid * 2 + 1];
    const float4* Wr = (const float4*)&W_hh[tid * 64];
    if (tid < HDIM) tht[tid] = 0.0f;
    float ct = 0.0f;
    __syncthreads();
    for (int t = 0; t < OBS; ++t) {
      const float x0 = tgt[t * 2], x1 = tgt[t * 2 + 1];
      float acc = bias + x0 * wi0 + x1 * wi1;
#pragma unroll
      for (int k4 = 0; k4 < 16; ++k4) {
        const float4 wv = Wr[k4];
        const float4 hv = *(const float4*)&tht[k4 * 4];
        acc += wv.x * hv.x + wv.y * hv.y + wv.z * hv.z + wv.w * hv.w;
      }
      tgb[tid] = acc;
      __syncthreads();
      if (tid < HDIM) {
        const float cn =
            sigm(tgb[64 + tid]) * ct + sigm(tgb[tid]) * tanh_(tgb[128 + tid]);
        ct = cn;
        tht[tid] = sigm(tgb[192 + tid]) * tanh_(cn);
      }
      __syncthreads();
    }
    if (tid < HDIM) ht_out[tid] = tht[tid];
    return;
  }

  const int l = tid & 63;
  const int w = tid >> 6;   // wave id 0..3 -> owns hidden dims w*16..w*16+15
  const int t15 = l & 15;   // = neighbor (within group) for B and D
  const int g4 = l >> 4;    // k-block
  const int n0 = blockIdx.x * NPB;

  // ---- stage x hi/lo MFMA table + last-step raw positions ----
  for (int i = tid; i < OBS * NPB; i += 256) {
    const int t = i >> 5, n = i & 31;
    const int gn = n0 + n;
    float x0 = 0.0f, x1 = 0.0f;
    if (gn < NTOT) {
      x0 = oth[(t * NTOT + gn) * 2 + 0];
      x1 = oth[(t * NTOT + gn) * 2 + 1];
    }
    const unsigned short xh0 = f2bf(x0);
    const unsigned short xl0 = f2bf(x0 - bf2f(xh0));
    const unsigned short xh1 = f2bf(x1);
    const unsigned short xl1 = f2bf(x1 - bf2f(xh1));
    u32x4 d;
    d.x = (unsigned)xh0 | ((unsigned)xh0 << 16);  // k0=x0hi k1=x0hi
    d.y = (unsigned)xl0 | ((unsigned)xh1 << 16);  // k2=x0lo k3=x1hi
    d.z = (unsigned)xh1 | ((unsigned)xl1 << 16);  // k4=x1hi k5=x1lo
    d.w = 0x3F803F80u;                            // k6=1    k7=1
    *(u32x4*)&xbf[i * 8] = d;
    if (t == OBS - 1) { xs14[n][0] = x0; xs14[n][1] = x1; }
  }
  if (tid == 0) {
    u32x4 zz = {0u, 0u, 0u, 0u};
    *(u32x4*)&xbf[ZOFF] = zz;
  }
  // zero h buffer 0 (both groups): 4096 B
  for (int i = tid; i < 1024; i += 256) ((unsigned*)hbuf[0])[i] = 0u;

  // ---- persistent A fragments: W_hh rows, hi/lo split (A row = l&15 = gate
  // within tile; k = kt*32 + g4*8 + j). Identical indexing to the proven LOADB.
  short8 A00, A01, A10, A11, A20, A21, A30, A31;
  short8 L00, L01, L10, L11, L20, L21, L30, L31;
#define LOADW(q, kt, AH, AL)                                                  \
  {                                                                           \
    const float* wp = &W_hh[(q * 64 + w * 16 + t15) * 64 + kt * 32 + g4 * 8]; \
    _Pragma("unroll") for (int j = 0; j < 8; ++j) {                           \
      float wv = wp[j];                                                       \
      unsigned short hi = f2bf(wv);                                           \
      unsigned short lo = f2bf(wv - bf2f(hi));                                \
      AH[j] = (short)hi;                                                      \
      AL[j] = (short)lo;                                                      \
    }                                                                         \
  }
  LOADW(0, 0, A00, L00) LOADW(0, 1, A01, L01)
  LOADW(1, 0, A10, L10) LOADW(1, 1, A11, L11)
  LOADW(2, 0, A20, L20) LOADW(2, 1, A21, L21)
  LOADW(3, 0, A30, L30) LOADW(3, 1, A31, L31)
#undef LOADW

  // ---- A_x fragments (x-part + bias as MFMA). Only k=0..7 rows nonzero.
  // Pairs with xbf rows: W0hi,W0lo,W0hi,W1hi,W1lo,W1hi,bias_hi,bias_lo.
  short8 X0, X1, X2, X3;
  {
    u32x4 z4 = {0u, 0u, 0u, 0u};
    X0 = X1 = X2 = X3 = __builtin_bit_cast(short8, z4);
    if (g4 == 0) {
#pragma unroll
      for (int q = 0; q < 4; ++q) {
        const int G = q * 64 + w * 16 + t15;
        const float w0 = W_ih[G * 2 + 0], w1 = W_ih[G * 2 + 1];
        const float bs = b_ih[G] + b_hh[G];
        const unsigned short w0h = f2bf(w0), w0l = f2bf(w0 - bf2f(w0h));
        const unsigned short w1h = f2bf(w1), w1l = f2bf(w1 - bf2f(w1h));
        const unsigned short bh = f2bf(bs), bl = f2bf(bs - bf2f(bh));
        u32x4 d;
        d.x = (unsigned)w0h | ((unsigned)w0l << 16);
        d.y = (unsigned)w0h | ((unsigned)w1h << 16);
        d.z = (unsigned)w1l | ((unsigned)w1h << 16);
        d.w = (unsigned)bh | ((unsigned)bl << 16);
        const short8 v = __builtin_bit_cast(short8, d);
        if (q == 0) X0 = v;
        else if (q == 1) X1 = v;
        else if (q == 2) X2 = v;
        else X3 = v;
      }
    }
  }

  // ---- LDS offsets (bytes within a 2048B group buffer), XOR swizzle by n&7
  const int swz = (t15 & 7) << 4;
  const int hr0 = t15 * 128 + ((g4 * 16) ^ swz);        // B read, kt=0
  const int hr1 = t15 * 128 + (((g4 * 16) + 64) ^ swz); // B read, kt=1
  const int hw = t15 * 128 + (((w * 32) + (g4 * 8)) ^ swz); // h write (8B)
  int xo = (g4 == 0) ? (t15 * 8) : ZOFF;     // ushort index into xbf
  const int xst = (g4 == 0) ? (NPB * 8) : 0; // per-step advance
  const int xg1 = (g4 == 0) ? 128 : 0;       // group1 delta (16 n * 8 ushort)

  f32x4 c0 = {0.f, 0.f, 0.f, 0.f}, c1 = {0.f, 0.f, 0.f, 0.f};
  const float refx = tgt[(OBS - 1) * 2 + 0];
  const float refy = tgt[(OBS - 1) * 2 + 1];

  __syncthreads();

  for (int t = 0; t < OBS; ++t) {
    const int cur = t & 1, nxt = cur ^ 1;
    const unsigned char* hb0 = hbuf[cur][0];
    const unsigned char* hb1 = hbuf[cur][1];
    const short8 Bx0 = *(const short8*)&xbf[xo];
    const short8 Bx1 = *(const short8*)&xbf[xo + xg1];
    const short8 B00 = *(const short8*)(hb0 + hr0);
    const short8 B01 = *(const short8*)(hb0 + hr1);
    const short8 B10 = *(const short8*)(hb1 + hr0);
    const short8 B11 = *(const short8*)(hb1 + hr1);
    xo += xst;

    const f32x4 z = {0.f, 0.f, 0.f, 0.f};
    // group 0
    f32x4 p0 = MFMA_BF16(X0, Bx0, z, 0, 0, 0);
    f32x4 p1 = MFMA_BF16(X1, Bx0, z, 0, 0, 0);
    f32x4 p2 = MFMA_BF16(X2, Bx0, z, 0, 0, 0);
    f32x4 p3 = MFMA_BF16(X3, Bx0, z, 0, 0, 0);
    p0 = MFMA_BF16(A00, B00, p0, 0, 0, 0);
    p1 = MFMA_BF16(A10, B00, p1, 0, 0, 0);
    p2 = MFMA_BF16(A20, B00, p2, 0, 0, 0);
    p3 = MFMA_BF16(A30, B00, p3, 0, 0, 0);
    p0 = MFMA_BF16(A01, B01, p0, 0, 0, 0);
    p1 = MFMA_BF16(A11, B01, p1, 0, 0, 0);
    p2 = MFMA_BF16(A21, B01, p2, 0, 0, 0);
    p3 = MFMA_BF16(A31, B01, p3, 0, 0, 0);
    p0 = MFMA_BF16(L00, B00, p0, 0, 0, 0);
    p1 = MFMA_BF16(L10, B00, p1, 0, 0, 0);
    p2 = MFMA_BF16(L20, B00, p2, 0, 0, 0);
    p3 = MFMA_BF16(L30, B00, p3, 0, 0, 0);
    p0 = MFMA_BF16(L01, B01, p0, 0, 0, 0);
    p1 = MFMA_BF16(L11, B01, p1, 0, 0, 0);
    p2 = MFMA_BF16(L21, B01, p2, 0, 0, 0);
    p3 = MFMA_BF16(L31, B01, p3, 0, 0, 0);
    // group 1
    f32x4 q0 = MFMA_BF16(X0, Bx1, z, 0, 0, 0);
    f32x4 q1 = MFMA_BF16(X1, Bx1, z, 0, 0, 0);
    f32x4 q2 = MFMA_BF16(X2, Bx1, z, 0, 0, 0);
    f32x4 q3 = MFMA_BF16(X3, Bx1, z, 0, 0, 0);
    q0 = MFMA_BF16(A00, B10, q0, 0, 0, 0);
    q1 = MFMA_BF16(A10, B10, q1, 0, 0, 0);
    q2 = MFMA_BF16(A20, B10, q2, 0, 0, 0);
    q3 = MFMA_BF16(A30, B10, q3, 0, 0, 0);
    q0 = MFMA_BF16(A01, B11, q0, 0, 0, 0);
    q1 = MFMA_BF16(A11, B11, q1, 0, 0, 0);
    q2 = MFMA_BF16(A21, B11, q2, 0, 0, 0);
    q3 = MFMA_BF16(A31, B11, q3, 0, 0, 0);
    q0 = MFMA_BF16(L00, B10, q0, 0, 0, 0);
    q1 = MFMA_BF16(L10, B10, q1, 0, 0, 0);
    q2 = MFMA_BF16(L20, B10, q2, 0, 0, 0);
    q3 = MFMA_BF16(L30, B10, q3, 0, 0, 0);
    q0 = MFMA_BF16(L01, B11, q0, 0, 0, 0);
    q1 = MFMA_BF16(L11, B11, q1, 0, 0, 0);
    q2 = MFMA_BF16(L21, B11, q2, 0, 0, 0);
    q3 = MFMA_BF16(L31, B11, q3, 0, 0, 0);

    if (t < OBS - 1) {
#define ACT(P0, P1, P2, P3, C, WB)                              \
  {                                                             \
    float hv[4];                                                \
    _Pragma("unroll") for (int r = 0; r < 4; ++r) {             \
      const float gi = P0[r], gf = P1[r], gg = P2[r],           \
                  go = P3[r];                                   \
      const float cn = sigm(gf) * C[r] + sigm(gi) * tanh_(gg);  \
      C[r] = cn;                                                \
      hv[r] = sigm(go) * tanh_(cn);                             \
    }                                                           \
    u32x2 pk;                                                   \
    pk.x = cvtpk_bf16(hv[0], hv[1]);                            \
    pk.y = cvtpk_bf16(hv[2], hv[3]);                            \
    *(u32x2*)(WB) = pk;                                         \
  }
      ACT(p0, p1, p2, p3, c0, hbuf[nxt][0] + hw)
      ACT(q0, q1, q2, q3, c1, hbuf[nxt][1] + hw)
#undef ACT
      __syncthreads();
    } else {
      // final step: compute h (fp32) and pool directly
#define POOL(P0, P1, P2, P3, C, G)                                         \
  {                                                                        \
    const int nl = G * 16 + t15;                                           \
    const int gn = n0 + nl;                                                \
    float hv[4];                                                           \
    _Pragma("unroll") for (int r = 0; r < 4; ++r) {                        \
      const float gi = P0[r], gf = P1[r], gg = P2[r], go = P3[r];          \
      const float cn = sigm(gf) * C[r] + sigm(gi) * tanh_(gg);             \
      hv[r] = sigm(go) * tanh_(cn);                                        \
    }                                                                      \
    const float rx = xs14[nl][0] - refx;                                   \
    const float ry = xs14[nl][1] - refy;                                   \
    bool ok = (fabsf(rx) <= 2.0f) && (fabsf(ry) <= 2.0f) && (gn < NTOT);   \
    const int cx = (int)truncf(rx) + 2; /* cw == 1.0 */                    \
    const int cy = (int)truncf(ry) + 2;                                    \
    ok = ok && (cx >= 0) && (cx < 4) && (cy >= 0) && (cy < 4);             \
    if (ok && mask[(OBS - 1) * NTOT + gn] != 0) {                          \
      float* sp = &social[(cy * 4 + cx) * HDIM + w * 16 + g4 * 4];         \
      _Pragma("unroll") for (int r = 0; r < 4; ++r)                        \
        atomicAdd(&sp[r], hv[r]);                                          \
    }                                                                      \
  }
      POOL(p0, p1, p2, p3, c0, 0)
      POOL(q0, q1, q2, q3, c1, 1)
#undef POOL
    }
  }
}

__global__ __launch_bounds__(512) void k_final(
    const float* __restrict__ W1, const float* __restrict__ b1,
    const float* __restrict__ W2, const float* __restrict__ b2,
    const float* __restrict__ Wc, const float* __restrict__ bc,
    const float* __restrict__ social, const float* __restrict__ ht_g,
    float* __restrict__ out)
{
  __shared__ float sv[1024];
  __shared__ float hid[64];
  __shared__ float comb[64];
  __shared__ float ht[64];

  const int tid = threadIdx.x;
  for (int i = tid; i < 1024; i += 512) sv[i] = social[i];
  if (tid < 64) ht[tid] = ht_g[tid];
  __syncthreads();

  const int wv = tid >> 6, ln = tid & 63;
  for (int o = wv; o < 64; o += 8) {
    float p = 0.0f;
#pragma unroll
    for (int it = 0; it < 16; ++it) {
      const int j = it * 64 + ln;
      p += sv[j] * W1[o * 1024 + j];
    }
#pragma unroll
    for (int off = 32; off > 0; off >>= 1) p += __shfl_down(p, off);
    if (ln == 0) hid[o] = fmaxf(p + b1[o], 0.0f);
  }
  __syncthreads();
  for (int o = wv; o < 64; o += 8) {
    float p = hid[ln] * W2[o * 64 + ln];
#pragma unroll
    for (int off = 32; off > 0; off >>= 1) p += __shfl_down(p, off);
    if (ln == 0) comb[o] = ht[o] + p + b2[o];
  }
  __syncthreads();
  if (wv < 2) {
    float p = comb[ln] * Wc[wv * 64 + ln];
#pragma unroll
    for (int off = 32; off > 0; off >>= 1) p += __shfl_down(p, off);
    if (ln == 0) out[wv] = p + bc[wv];
  }
}

extern "C" void kernel_launch(void* const* d_in, const int* in_sizes, int n_in,
                              void* d_out, int out_size, void* d_ws, size_t ws_size,
                              hipStream_t stream) {
  const float* tgt = (const float*)d_in[0];
  const float* oth = (const float*)d_in[1];
  const int* mask = (const int*)d_in[2];
  const float* W_ih = (const float*)d_in[3];
  const float* b_ih = (const float*)d_in[4];
  const float* W_hh = (const float*)d_in[5];
  const float* b_hh = (const float*)d_in[6];
  const float* W1 = (const float*)d_in[7];
  const float* b1 = (const float*)d_in[8];
  const float* W2 = (const float*)d_in[9];
  const float* b2 = (const float*)d_in[10];
  const float* Wc = (const float*)d_in[11];
  const float* bc = (const float*)d_in[12];
  float* social = (float*)d_ws;          // ws[0..1023]
  float* ht = social + 1024;             // ws[1024..1087] (target-LSTM h)
  float* out = (float*)d_out;

  hipLaunchKernelGGL(k_zero, dim3(1), dim3(1024), 0, stream, social);
  hipLaunchKernelGGL(k_neigh, dim3(NBLK_N + 1), dim3(256), 0, stream,
                     tgt, oth, mask, W_ih, b_ih, W_hh, b_hh, social, ht);
  hipLaunchKernelGGL(k_final, dim3(1), dim3(512), 0, stream,
                     W1, b1, W2, b2, Wc, bc, social, ht, out);
}